// Round 2
// baseline (257.060 us; speedup 1.0000x reference)
//
#include <hip/hip_runtime.h>
#include <math.h>

#define D_CH 2048
#define LSEQ 8192
#define T1 32
#define NC1 256          // LSEQ / T1
#define VSLAB 524288     // per-slab V floats (8192*64)

typedef __attribute__((ext_vector_type(8))) short bf16x8;
typedef __attribute__((ext_vector_type(4))) float f32x4;

__device__ __forceinline__ short f2bf(float x) {
  unsigned u = __float_as_uint(x);
  u += 0x7FFFu + ((u >> 16) & 1);       // round-to-nearest-even
  return (short)(u >> 16);
}

// ---------------------------------------------------------------------------
// fp32 4x4-register-tile 64x64 matmul helpers on LDS (numerically critical
// dA-power chain stays fp32: squaring DOUBLES relative exponent error, so
// bf16 squarings diverge — measured round 5: 65% output error).
// ---------------------------------------------------------------------------
__device__ __forceinline__ void mmzero(float acc[16]) {
#pragma unroll
  for (int t = 0; t < 16; ++t) acc[t] = 0.f;
}

template <int SZ>
__device__ __forceinline__ void mmld(float acc[16], const float* __restrict__ Z,
                                     int r0, int c0) {
#pragma unroll
  for (int i = 0; i < 4; ++i) {
    float4 z = *(const float4*)&Z[(r0 + i) * SZ + c0];
    acc[i * 4 + 0] = z.x; acc[i * 4 + 1] = z.y;
    acc[i * 4 + 2] = z.z; acc[i * 4 + 3] = z.w;
  }
}

template <int SX, int SY>
__device__ __forceinline__ void mac44(float acc[16], const float* __restrict__ Xb,
                                      const float* __restrict__ Yb, int r0, int c0) {
#pragma unroll 4
  for (int k = 0; k < 64; k += 4) {
    float4 x0 = *(const float4*)&Xb[(r0 + 0) * SX + k];
    float4 x1 = *(const float4*)&Xb[(r0 + 1) * SX + k];
    float4 x2 = *(const float4*)&Xb[(r0 + 2) * SX + k];
    float4 x3 = *(const float4*)&Xb[(r0 + 3) * SX + k];
    float4 y0 = *(const float4*)&Yb[(k + 0) * SY + c0];
    float4 y1 = *(const float4*)&Yb[(k + 1) * SY + c0];
    float4 y2 = *(const float4*)&Yb[(k + 2) * SY + c0];
    float4 y3 = *(const float4*)&Yb[(k + 3) * SY + c0];
#define MROW(i, xi) \
    acc[i * 4 + 0] += xi.x * y0.x + xi.y * y1.x + xi.z * y2.x + xi.w * y3.x; \
    acc[i * 4 + 1] += xi.x * y0.y + xi.y * y1.y + xi.z * y2.y + xi.w * y3.y; \
    acc[i * 4 + 2] += xi.x * y0.z + xi.y * y1.z + xi.z * y2.z + xi.w * y3.z; \
    acc[i * 4 + 3] += xi.x * y0.w + xi.y * y1.w + xi.z * y2.w + xi.w * y3.w;
    MROW(0, x0) MROW(1, x1) MROW(2, x2) MROW(3, x3)
#undef MROW
  }
}

template <int SZ>
__device__ __forceinline__ void mmst(float* Dst, const float acc[16], int r0, int c0) {
#pragma unroll
  for (int i = 0; i < 4; ++i)
    *(float4*)&Dst[(r0 + i) * SZ + c0] =
        make_float4(acc[i * 4 + 0], acc[i * 4 + 1], acc[i * 4 + 2], acc[i * 4 + 3]);
}

// ---------------------------------------------------------------------------
// main_kernel:
//   block 0: prep — fp32 Q-chain (2-buffer, register-held step products)
//            -> invdT (delta*Q^T), dA = 2Q-I
//   blocks 1..: V[slab] = B @ X  (bf16 MFMA, 32t x 64n tiles, K-slab,
//            register prefetch of next K-step).  LDS union 34.8 KB ->
//            4 blocks/CU (was 52.2 KB / 3), grid nslab*256+1 -> 4 res/CU.
// ---------------------------------------------------------------------------
__global__ __launch_bounds__(256) void main_kernel(const float* __restrict__ X,
                                                   const float* __restrict__ A,
                                                   const float* __restrict__ B,
                                                   const float* __restrict__ logd,
                                                   float* __restrict__ invdT,
                                                   float* __restrict__ dAg,
                                                   float* __restrict__ V,
                                                   int KS) {
  __shared__ float smem[8704];           // 34.8 KB union
  const int tid = threadIdx.x;
  const int lane = tid & 63;
  const int w = tid >> 6;

  if (blockIdx.x == 0) {
    // ---------------- Q-chain (fp32): Q ~= inv(I - P), ||P|| <= ~0.12 ------
    // 2 buffers: bQ (running series), bP (running power). Step products are
    // held in registers across a barrier, then both stored back.
    float* bQ = smem;
    float* bP = smem + 4352;
    const int r0 = (tid >> 4) * 4, c0 = (tid & 15) * 4;
    const float delta = expf(logd[0]);
    const float half = 0.5f * delta;
    float accQ[16], accP[16];

    for (int idx = tid; idx < 4096; idx += 256) {
      int i = idx >> 6, j = idx & 63;
      float p = half * A[idx];
      bP[i * 68 + j] = p;
      bQ[i * 68 + j] = p + (i == j ? 1.f : 0.f);   // S2 = I + P
    }
    __syncthreads();
    // bP = P^2
    mmzero(accP); mac44<68, 68>(accP, bP, bP, r0, c0);
    __syncthreads();
    mmst<68>(bP, accP, r0, c0);
    __syncthreads();
    // 3 doublings: (S_{2k}, P^{2k}) -> (S_{4k}, P^{4k}); last skips P update.
    // S16 = series of P through P^15 (same arithmetic/order as 3-buffer ver.)
#pragma unroll 1
    for (int s = 0; s < 3; ++s) {
      mmld<68>(accQ, bQ, r0, c0);
      mac44<68, 68>(accQ, bP, bQ, r0, c0);        // Q + P^k * Q
      if (s < 2) { mmzero(accP); mac44<68, 68>(accP, bP, bP, r0, c0); }
      __syncthreads();
      mmst<68>(bQ, accQ, r0, c0);
      if (s < 2) mmst<68>(bP, accP, r0, c0);
      __syncthreads();
    }

    // exports: invdT = delta*Q^T, dA = 2Q - I
    for (int idx = tid; idx < 4096; idx += 256) {
      int n = idx >> 6, m = idx & 63;
      float qv = bQ[n * 68 + m];
      invdT[m * 64 + n] = delta * qv;
      dAg[idx] = 2.f * qv - (n == m ? 1.f : 0.f);
    }
    return;
  }

  // ------------------------------ vgemm (bf16 MFMA) ------------------------
  // 32t x 64n output tile, K-slab of KS, 64-k steps with register prefetch.
  const int b = blockIdx.x - 1;
  const int t0 = (b & 255) << 5;         // 256 t-tiles of 32
  const int slab = b >> 8;
  const int k0 = slab * KS;
  short* Xs = (short*)smem;              // [32][72] bf16  (t-major)
  short* Bs = (short*)smem + 2304;       // [64][72] bf16  (n-major)
  const int q = lane >> 4, r = lane & 15;
  const int hi = lane >> 5, tl = lane & 31;
  const int brow = lane >> 3;            // 0..7
  const int bkc = (lane & 7) * 8;        // 0..56
  const int wm = (w & 1) * 16;           // M-half of this wave
  const int wn = (w >> 1) * 32;          // N-half of this wave

  f32x4 acc[2];
#pragma unroll
  for (int j = 0; j < 2; ++j) acc[j] = (f32x4){0.f, 0.f, 0.f, 0.f};

  float xv[8];
  float bv[16];

#define LOADX(KK)                                                              \
  _Pragma("unroll")                                                            \
  for (int j = 0; j < 8; ++j)                                                  \
    xv[j] = X[(size_t)(k0 + (KK) + w * 16 + hi * 8 + j) * LSEQ + t0 + tl];

#define LOADB(KK)                                                              \
  _Pragma("unroll")                                                            \
  for (int p = 0; p < 2; ++p) {                                                \
    int n = p * 32 + w * 8 + brow;                                             \
    float4 f0 = *(const float4*)&B[(size_t)n * D_CH + k0 + (KK) + bkc];        \
    float4 f1 = *(const float4*)&B[(size_t)n * D_CH + k0 + (KK) + bkc + 4];    \
    bv[p * 8 + 0] = f0.x; bv[p * 8 + 1] = f0.y;                                \
    bv[p * 8 + 2] = f0.z; bv[p * 8 + 3] = f0.w;                                \
    bv[p * 8 + 4] = f1.x; bv[p * 8 + 5] = f1.y;                                \
    bv[p * 8 + 6] = f1.z; bv[p * 8 + 7] = f1.w;                                \
  }

  LOADX(0)
  LOADB(0)

  for (int kk = 0; kk < KS; kk += 64) {
    // cvt + LDS write of the tile staged in registers
    bf16x8 xp;
#pragma unroll
    for (int j = 0; j < 8; ++j) xp[j] = f2bf(xv[j]);
    *(bf16x8*)&Xs[tl * 72 + w * 16 + hi * 8] = xp;
#pragma unroll
    for (int p = 0; p < 2; ++p) {
      bf16x8 bp8;
#pragma unroll
      for (int j = 0; j < 8; ++j) bp8[j] = f2bf(bv[p * 8 + j]);
      *(bf16x8*)&Bs[(p * 32 + w * 8 + brow) * 72 + bkc] = bp8;
    }
    __syncthreads();

    // prefetch next K-step into registers (overlaps MFMA + barrier)
    if (kk + 64 < KS) {
      LOADX(kk + 64)
      LOADB(kk + 64)
    }

#pragma unroll
    for (int ks = 0; ks < 64; ks += 32) {
      bf16x8 a = *(const bf16x8*)&Xs[(wm + r) * 72 + ks + q * 8];
#pragma unroll
      for (int j = 0; j < 2; ++j) {
        bf16x8 bb = *(const bf16x8*)&Bs[(wn + j * 16 + r) * 72 + ks + q * 8];
        acc[j] = __builtin_amdgcn_mfma_f32_16x16x32_bf16(a, bb, acc[j], 0, 0, 0);
      }
    }
    __syncthreads();
  }
#undef LOADX
#undef LOADB

  float* Vs = V + (size_t)slab * VSLAB;
#pragma unroll
  for (int j = 0; j < 2; ++j)
#pragma unroll
    for (int reg = 0; reg < 4; ++reg)
      Vs[(size_t)(t0 + wm + q * 4 + reg) * 64 + wn + j * 16 + r] = acc[j][reg];
}

// ---------------------------------------------------------------------------
// matvec step: h' = M h + u, h broadcast via LDS ping-pong
// ---------------------------------------------------------------------------
__device__ __forceinline__ float matvec(const float ar[64], const float* __restrict__ hb,
                                        float u) {
  float a0 = u, a1 = 0.f, a2 = 0.f, a3 = 0.f;
#pragma unroll
  for (int jj = 0; jj < 64; jj += 4) {
    float4 hv = *(const float4*)&hb[jj];
    a0 += ar[jj + 0] * hv.x;
    a1 += ar[jj + 1] * hv.y;
    a2 += ar[jj + 2] * hv.z;
    a3 += ar[jj + 3] * hv.w;
  }
  return (a0 + a1) + (a2 + a3);
}

// ---------------------------------------------------------------------------
// scan1: blocks 0..NC1-1: U-chunk = invd applied to sum of V slabs, then
// wave 0 does the serial 32-step chunk summary.
// block NC1: 9 fp32 squarings of dA -> dA^32, dA^512 (for mid, next launch).
// ---------------------------------------------------------------------------
__global__ __launch_bounds__(256) void scan1_kernel(const float* __restrict__ V,
                                                    const float* __restrict__ invdT,
                                                    const float* __restrict__ dA,
                                                    float* __restrict__ U,
                                                    float* __restrict__ S,
                                                    float* __restrict__ dA32g,
                                                    float* __restrict__ dA512g,
                                                    int nslab) {
  __shared__ float smem[8704];
  const int tid = threadIdx.x;
  const int c = blockIdx.x;

  if (c == NC1) {
    // fp32 squaring chain (numerically critical — see header comment)
    float* b0 = smem;
    float* b1 = smem + 4352;
    const int r0 = (tid >> 4) * 4, c0 = (tid & 15) * 4;
    for (int idx = tid; idx < 4096; idx += 256)
      b0[(idx >> 6) * 68 + (idx & 63)] = dA[idx];
    __syncthreads();
    float acc[16];
    float* p = b0; float* q = b1;
    for (int s = 1; s <= 9; ++s) {
      mmzero(acc); mac44<68, 68>(acc, p, p, r0, c0);
      if (s == 5) mmst<64>(dA32g, acc, r0, c0);
      if (s == 9) mmst<64>(dA512g, acc, r0, c0);
      mmst<68>(q, acc, r0, c0);
      __syncthreads();
      float* t = p; p = q; q = t;
    }
    return;
  }

  float* invs = smem;            // 4096
  float* Vs   = smem + 4096;     // 2048
  float* Us   = smem + 6144;     // 2048
  float* hs0  = smem + 8192;     // 64
  float* hs1  = smem + 8256;     // 64

  for (int idx = tid; idx < 4096; idx += 256) invs[idx] = invdT[idx];
  for (int idx = tid; idx < 2048; idx += 256) {
    float v = 0.f;
    for (int s = 0; s < nslab; ++s) v += V[(size_t)s * VSLAB + (size_t)c * 2048 + idx];
    Vs[idx] = v;
  }
  __syncthreads();

  // transform: 2 rows x 4 cols per thread
  const int r0 = (tid >> 4) * 2, c0 = (tid & 15) * 4;
  float a0[4] = {0.f, 0.f, 0.f, 0.f}, a1[4] = {0.f, 0.f, 0.f, 0.f};
#pragma unroll 4
  for (int k = 0; k < 64; k += 4) {
    float4 v0 = *(const float4*)&Vs[r0 * 64 + k];
    float4 v1 = *(const float4*)&Vs[(r0 + 1) * 64 + k];
    float4 y0 = *(const float4*)&invs[(k + 0) * 64 + c0];
    float4 y1 = *(const float4*)&invs[(k + 1) * 64 + c0];
    float4 y2 = *(const float4*)&invs[(k + 2) * 64 + c0];
    float4 y3 = *(const float4*)&invs[(k + 3) * 64 + c0];
    a0[0] += v0.x * y0.x + v0.y * y1.x + v0.z * y2.x + v0.w * y3.x;
    a0[1] += v0.x * y0.y + v0.y * y1.y + v0.z * y2.y + v0.w * y3.y;
    a0[2] += v0.x * y0.z + v0.y * y1.z + v0.z * y2.z + v0.w * y3.z;
    a0[3] += v0.x * y0.w + v0.y * y1.w + v0.z * y2.w + v0.w * y3.w;
    a1[0] += v1.x * y0.x + v1.y * y1.x + v1.z * y2.x + v1.w * y3.x;
    a1[1] += v1.x * y0.y + v1.y * y1.y + v1.z * y2.y + v1.w * y3.y;
    a1[2] += v1.x * y0.z + v1.y * y1.z + v1.z * y2.z + v1.w * y3.z;
    a1[3] += v1.x * y0.w + v1.y * y1.w + v1.z * y2.w + v1.w * y3.w;
  }
  *(float4*)&Us[r0 * 64 + c0] = make_float4(a0[0], a0[1], a0[2], a0[3]);
  *(float4*)&Us[(r0 + 1) * 64 + c0] = make_float4(a1[0], a1[1], a1[2], a1[3]);
  *(float4*)&U[(size_t)(c * 32 + r0) * 64 + c0] = make_float4(a0[0], a0[1], a0[2], a0[3]);
  *(float4*)&U[(size_t)(c * 32 + r0 + 1) * 64 + c0] = make_float4(a1[0], a1[1], a1[2], a1[3]);
  __syncthreads();

  if (tid < 64) {
    float ar[64];
#pragma unroll
    for (int jj = 0; jj < 64; jj += 4) {
      float4 v = *(const float4*)&dA[tid * 64 + jj];
      ar[jj] = v.x; ar[jj + 1] = v.y; ar[jj + 2] = v.z; ar[jj + 3] = v.w;
    }
    float h = 0.f;
    hs0[tid] = 0.f;
    for (int t = 0; t < T1; ++t) {
      float u = Us[t * 64 + tid];
      h = matvec(ar, (t & 1) ? hs1 : hs0, u);
      ((t & 1) ? hs0 : hs1)[tid] = h;
    }
    S[c * 64 + tid] = h;
  }
}

// ---------------------------------------------------------------------------
// mid: 3 middle levels in one block (16 waves), round-4 proven.
// __launch_bounds__(1024, 4): 16 waves = 4 waves/SIMD at 1 block/CU ->
// VGPR cap 128 (was 64: ar[64] spilled to scratch, 57 us latency chain).
// ar/br live ranges are scope-split so they never coexist; ar is reloaded
// from dA32 (16 KB, L2-warm) for phase 3 instead of staying live through
// phase 2.
// ---------------------------------------------------------------------------
__global__ __launch_bounds__(1024, 4) void mid_kernel(const float* __restrict__ S,
                                                      const float* __restrict__ dA32,
                                                      const float* __restrict__ dA512,
                                                      float* __restrict__ Hinit) {
  __shared__ float S2s[1024];
  __shared__ float H2s[1024];
  __shared__ float hsbuf[2048];
  const int tid = threadIdx.x;
  const int wave = tid >> 6, lane = tid & 63;
  float* hs0 = &hsbuf[wave * 128];
  float* hs1 = hs0 + 64;
  const float* inw = S + wave * 16 * 64;

  // ---- phase 1: 16 parallel 16-step scans with dA32 ----
  {
    float ar[64];
#pragma unroll
    for (int jj = 0; jj < 64; jj += 4) {
      float4 v = *(const float4*)&dA32[lane * 64 + jj];
      ar[jj] = v.x; ar[jj + 1] = v.y; ar[jj + 2] = v.z; ar[jj + 3] = v.w;
    }
    float h = 0.f;
    hs0[lane] = 0.f;
    for (int t = 0; t < 16; ++t) {
      float u = inw[t * 64 + lane];
      h = matvec(ar, (t & 1) ? hs1 : hs0, u);
      ((t & 1) ? hs0 : hs1)[lane] = h;
    }
    S2s[wave * 64 + lane] = h;
  }
  __syncthreads();

  // ---- phase 2: wave 0 scans the 16 summaries with dA512 ----
  if (wave == 0) {
    float br[64];
#pragma unroll
    for (int jj = 0; jj < 64; jj += 4) {
      float4 v = *(const float4*)&dA512[lane * 64 + jj];
      br[jj] = v.x; br[jj + 1] = v.y; br[jj + 2] = v.z; br[jj + 3] = v.w;
    }
    float g = 0.f;
    hs0[lane] = 0.f;
    for (int t = 0; t < 16; ++t) {
      H2s[t * 64 + lane] = g;
      float u = S2s[t * 64 + lane];
      g = matvec(br, (t & 1) ? hs1 : hs0, u);
      ((t & 1) ? hs0 : hs1)[lane] = g;
    }
  }
  __syncthreads();

  // ---- phase 3: re-expand with dA32 (ar reloaded; L2-warm) ----
  {
    float ar[64];
#pragma unroll
    for (int jj = 0; jj < 64; jj += 4) {
      float4 v = *(const float4*)&dA32[lane * 64 + jj];
      ar[jj] = v.x; ar[jj + 1] = v.y; ar[jj + 2] = v.z; ar[jj + 3] = v.w;
    }
    float h = H2s[wave * 64 + lane];
    hs0[lane] = h;
    for (int t = 0; t < 16; ++t) {
      Hinit[(wave * 16 + t) * 64 + lane] = h;
      float u = inw[t * 64 + lane];
      h = matvec(ar, (t & 1) ? hs1 : hs0, u);
      ((t & 1) ? hs0 : hs1)[lane] = h;
    }
  }
}

// ---------------------------------------------------------------------------
// scan2: one wave/block, full-state expansion with 4-deep prefetch ring.
// ---------------------------------------------------------------------------
__global__ __launch_bounds__(64) void scan2_kernel(const float* __restrict__ U,
                                                   const float* __restrict__ dA,
                                                   const float* __restrict__ Hinit,
                                                   float* __restrict__ Ht) {
  __shared__ float hs[2][64];
  const int tid = threadIdx.x;
  const int c = blockIdx.x;
  float ar[64];
#pragma unroll
  for (int jj = 0; jj < 64; jj += 4) {
    float4 v = *(const float4*)&dA[tid * 64 + jj];
    ar[jj] = v.x; ar[jj + 1] = v.y; ar[jj + 2] = v.z; ar[jj + 3] = v.w;
  }
  float h = Hinit[c * 64 + tid];
  hs[0][tid] = h;
  const float* inc = U + (size_t)c * T1 * 64;
  float* outc = Ht + (size_t)c * T1 * 64;
  float up[4];
#pragma unroll
  for (int i = 0; i < 4; ++i) up[i] = inc[i * 64 + tid];

  for (int t = 0; t < T1; ++t) {
    float u = up[t & 3];
    if (t + 4 < T1) up[t & 3] = inc[(t + 4) * 64 + tid];
    h = matvec(ar, hs[t & 1], u);
    hs[(t + 1) & 1][tid] = h;
    outc[t * 64 + tid] = h;
  }
}

// ---------------------------------------------------------------------------
// out: Y[d][t] = (C @ Ht^T)[d][t] + Dp[d]*X[d][t]  via bf16 MFMA (K = 64).
// ---------------------------------------------------------------------------
__global__ __launch_bounds__(256) void out_kernel(const float* __restrict__ X,
                                                  const float* __restrict__ C,
                                                  const float* __restrict__ Dp,
                                                  const float* __restrict__ Ht,
                                                  float* __restrict__ Y) {
  __shared__ short Cs[64 * 72];      // [d][n] bf16
  __shared__ short Hs[64 * 72];      // [t][n] bf16
  const int tid = threadIdx.x;
  const int lane = tid & 63, w = tid >> 6;
  const int t0 = blockIdx.x * 64;
  const int d0 = blockIdx.y * 64;
  const int q = lane >> 4, r = lane & 15;
  const int brow = lane >> 3, bkc = (lane & 7) * 8;

#pragma unroll
  for (int p = 0; p < 2; ++p) {
    int row = p * 32 + w * 8 + brow;
    float4 c0 = *(const float4*)&C[(size_t)(d0 + row) * 64 + bkc];
    float4 c1 = *(const float4*)&C[(size_t)(d0 + row) * 64 + bkc + 4];
    float4 h0 = *(const float4*)&Ht[(size_t)(t0 + row) * 64 + bkc];
    float4 h1 = *(const float4*)&Ht[(size_t)(t0 + row) * 64 + bkc + 4];
    bf16x8 cv, hv;
    cv[0] = f2bf(c0.x); cv[1] = f2bf(c0.y); cv[2] = f2bf(c0.z); cv[3] = f2bf(c0.w);
    cv[4] = f2bf(c1.x); cv[5] = f2bf(c1.y); cv[6] = f2bf(c1.z); cv[7] = f2bf(c1.w);
    hv[0] = f2bf(h0.x); hv[1] = f2bf(h0.y); hv[2] = f2bf(h0.z); hv[3] = f2bf(h0.w);
    hv[4] = f2bf(h1.x); hv[5] = f2bf(h1.y); hv[6] = f2bf(h1.z); hv[7] = f2bf(h1.w);
    *(bf16x8*)&Cs[row * 72 + bkc] = cv;
    *(bf16x8*)&Hs[row * 72 + bkc] = hv;
  }
  __syncthreads();

  f32x4 acc[4];
#pragma unroll
  for (int j = 0; j < 4; ++j) acc[j] = (f32x4){0.f, 0.f, 0.f, 0.f};
#pragma unroll
  for (int ks = 0; ks < 64; ks += 32) {
    bf16x8 a = *(const bf16x8*)&Cs[(w * 16 + r) * 72 + ks + q * 8];
#pragma unroll
    for (int j = 0; j < 4; ++j) {
      bf16x8 bb = *(const bf16x8*)&Hs[(j * 16 + r) * 72 + ks + q * 8];
      acc[j] = __builtin_amdgcn_mfma_f32_16x16x32_bf16(a, bb, acc[j], 0, 0, 0);
    }
  }

#pragma unroll
  for (int reg = 0; reg < 4; ++reg) {
    int d = d0 + w * 16 + q * 4 + reg;
    float dp = Dp[d];
#pragma unroll
    for (int j = 0; j < 4; ++j) {
      int t = t0 + j * 16 + r;
      size_t off = (size_t)d * LSEQ + t;
      Y[off] = acc[j][reg] + dp * X[off];
    }
  }
}

// ---------------------------------------------------------------------------
extern "C" void kernel_launch(void* const* d_in, const int* in_sizes, int n_in,
                              void* d_out, int out_size, void* d_ws, size_t ws_size,
                              hipStream_t stream) {
  const float* X  = (const float*)d_in[0];
  const float* A  = (const float*)d_in[1];
  const float* B  = (const float*)d_in[2];
  const float* Cm = (const float*)d_in[3];
  const float* Dp = (const float*)d_in[4];
  const float* ld = (const float*)d_in[5];
  float* out = (float*)d_out;
  float* ws = (float*)d_ws;

  // 4 K-slabs if workspace allows (10.2 MB), else 2 (6.2 MB)
  const size_t need4 = (size_t)(16384 + 4 * VSLAB + VSLAB + 16384 + 16384) * 4;
  const int nslab = (ws_size >= need4) ? 4 : 2;

  float* invdT = ws;                       // 4096
  float* dA    = ws + 4096;                // 4096
  float* dA32  = ws + 8192;                // 4096
  float* dA512 = ws + 12288;               // 4096
  float* V     = ws + 16384;               // nslab * 524288
  float* U     = V + (size_t)nslab * VSLAB; // 524288
  float* S     = U + VSLAB;                // 16384
  float* Hinit = S + 16384;                // 16384
  float* Ht    = V;                         // overlay: V dead after scan1

  main_kernel<<<nslab * 256 + 1, 256, 0, stream>>>(X, A, B, ld, invdT, dA, V,
                                                   2048 / nslab);
  scan1_kernel<<<NC1 + 1, 256, 0, stream>>>(V, invdT, dA, U, S, dA32, dA512, nslab);
  mid_kernel<<<1, 1024, 0, stream>>>(S, dA32, dA512, Hinit);
  scan2_kernel<<<NC1, 64, 0, stream>>>(U, dA, Hinit, Ht);
  out_kernel<<<dim3(128, 32), 256, 0, stream>>>(X, Cm, Dp, Ht, out);
}

// Round 3
// 254.863 us; speedup vs baseline: 1.0086x; 1.0086x over previous
//
#include <hip/hip_runtime.h>
#include <math.h>

#define D_CH 2048
#define LSEQ 8192
#define T1 32
#define NC1 256          // LSEQ / T1
#define VSLAB 524288     // per-slab V floats (8192*64)

typedef __attribute__((ext_vector_type(8))) short bf16x8;
typedef __attribute__((ext_vector_type(4))) float f32x4;

__device__ __forceinline__ short f2bf(float x) {
  unsigned u = __float_as_uint(x);
  u += 0x7FFFu + ((u >> 16) & 1);       // round-to-nearest-even
  return (short)(u >> 16);
}

// ---------------------------------------------------------------------------
// fp32 4x4-register-tile 64x64 matmul helpers on LDS (numerically critical
// dA-power chain stays fp32: squaring DOUBLES relative exponent error, so
// bf16 squarings diverge — measured round 5: 65% output error).
// ---------------------------------------------------------------------------
__device__ __forceinline__ void mmzero(float acc[16]) {
#pragma unroll
  for (int t = 0; t < 16; ++t) acc[t] = 0.f;
}

template <int SZ>
__device__ __forceinline__ void mmld(float acc[16], const float* __restrict__ Z,
                                     int r0, int c0) {
#pragma unroll
  for (int i = 0; i < 4; ++i) {
    float4 z = *(const float4*)&Z[(r0 + i) * SZ + c0];
    acc[i * 4 + 0] = z.x; acc[i * 4 + 1] = z.y;
    acc[i * 4 + 2] = z.z; acc[i * 4 + 3] = z.w;
  }
}

template <int SX, int SY>
__device__ __forceinline__ void mac44(float acc[16], const float* __restrict__ Xb,
                                      const float* __restrict__ Yb, int r0, int c0) {
#pragma unroll 4
  for (int k = 0; k < 64; k += 4) {
    float4 x0 = *(const float4*)&Xb[(r0 + 0) * SX + k];
    float4 x1 = *(const float4*)&Xb[(r0 + 1) * SX + k];
    float4 x2 = *(const float4*)&Xb[(r0 + 2) * SX + k];
    float4 x3 = *(const float4*)&Xb[(r0 + 3) * SX + k];
    float4 y0 = *(const float4*)&Yb[(k + 0) * SY + c0];
    float4 y1 = *(const float4*)&Yb[(k + 1) * SY + c0];
    float4 y2 = *(const float4*)&Yb[(k + 2) * SY + c0];
    float4 y3 = *(const float4*)&Yb[(k + 3) * SY + c0];
#define MROW(i, xi) \
    acc[i * 4 + 0] += xi.x * y0.x + xi.y * y1.x + xi.z * y2.x + xi.w * y3.x; \
    acc[i * 4 + 1] += xi.x * y0.y + xi.y * y1.y + xi.z * y2.y + xi.w * y3.y; \
    acc[i * 4 + 2] += xi.x * y0.z + xi.y * y1.z + xi.z * y2.z + xi.w * y3.z; \
    acc[i * 4 + 3] += xi.x * y0.w + xi.y * y1.w + xi.z * y2.w + xi.w * y3.w;
    MROW(0, x0) MROW(1, x1) MROW(2, x2) MROW(3, x3)
#undef MROW
  }
}

template <int SZ>
__device__ __forceinline__ void mmst(float* Dst, const float acc[16], int r0, int c0) {
#pragma unroll
  for (int i = 0; i < 4; ++i)
    *(float4*)&Dst[(r0 + i) * SZ + c0] =
        make_float4(acc[i * 4 + 0], acc[i * 4 + 1], acc[i * 4 + 2], acc[i * 4 + 3]);
}

// ---------------------------------------------------------------------------
// main_kernel:
//   block 0: prep — fp32 Q-chain (2-buffer, register-held step products)
//            -> invdT (delta*Q^T), dA = 2Q-I
//   blocks 1..: V[slab] = B @ X  (bf16 MFMA, 32t x 64n tiles, K-slab,
//            register prefetch of next K-step).  LDS union 34.8 KB ->
//            4 blocks/CU (was 52.2 KB / 3), grid nslab*256+1 -> 4 res/CU.
// ---------------------------------------------------------------------------
__global__ __launch_bounds__(256) void main_kernel(const float* __restrict__ X,
                                                   const float* __restrict__ A,
                                                   const float* __restrict__ B,
                                                   const float* __restrict__ logd,
                                                   float* __restrict__ invdT,
                                                   float* __restrict__ dAg,
                                                   float* __restrict__ V,
                                                   int KS) {
  __shared__ float smem[8704];           // 34.8 KB union
  const int tid = threadIdx.x;
  const int lane = tid & 63;
  const int w = tid >> 6;

  if (blockIdx.x == 0) {
    // ---------------- Q-chain (fp32): Q ~= inv(I - P), ||P|| <= ~0.12 ------
    // 2 buffers: bQ (running series), bP (running power). Step products are
    // held in registers across a barrier, then both stored back.
    float* bQ = smem;
    float* bP = smem + 4352;
    const int r0 = (tid >> 4) * 4, c0 = (tid & 15) * 4;
    const float delta = expf(logd[0]);
    const float half = 0.5f * delta;
    float accQ[16], accP[16];

    for (int idx = tid; idx < 4096; idx += 256) {
      int i = idx >> 6, j = idx & 63;
      float p = half * A[idx];
      bP[i * 68 + j] = p;
      bQ[i * 68 + j] = p + (i == j ? 1.f : 0.f);   // S2 = I + P
    }
    __syncthreads();
    // bP = P^2
    mmzero(accP); mac44<68, 68>(accP, bP, bP, r0, c0);
    __syncthreads();
    mmst<68>(bP, accP, r0, c0);
    __syncthreads();
    // 3 doublings: (S_{2k}, P^{2k}) -> (S_{4k}, P^{4k}); last skips P update.
    // S16 = series of P through P^15 (same arithmetic/order as 3-buffer ver.)
#pragma unroll 1
    for (int s = 0; s < 3; ++s) {
      mmld<68>(accQ, bQ, r0, c0);
      mac44<68, 68>(accQ, bP, bQ, r0, c0);        // Q + P^k * Q
      if (s < 2) { mmzero(accP); mac44<68, 68>(accP, bP, bP, r0, c0); }
      __syncthreads();
      mmst<68>(bQ, accQ, r0, c0);
      if (s < 2) mmst<68>(bP, accP, r0, c0);
      __syncthreads();
    }

    // exports: invdT = delta*Q^T, dA = 2Q - I
    for (int idx = tid; idx < 4096; idx += 256) {
      int n = idx >> 6, m = idx & 63;
      float qv = bQ[n * 68 + m];
      invdT[m * 64 + n] = delta * qv;
      dAg[idx] = 2.f * qv - (n == m ? 1.f : 0.f);
    }
    return;
  }

  // ------------------------------ vgemm (bf16 MFMA) ------------------------
  // 32t x 64n output tile, K-slab of KS, 64-k steps with register prefetch.
  const int b = blockIdx.x - 1;
  const int t0 = (b & 255) << 5;         // 256 t-tiles of 32
  const int slab = b >> 8;
  const int k0 = slab * KS;
  short* Xs = (short*)smem;              // [32][72] bf16  (t-major)
  short* Bs = (short*)smem + 2304;       // [64][72] bf16  (n-major)
  const int q = lane >> 4, r = lane & 15;
  const int hi = lane >> 5, tl = lane & 31;
  const int brow = lane >> 3;            // 0..7
  const int bkc = (lane & 7) * 8;        // 0..56
  const int wm = (w & 1) * 16;           // M-half of this wave
  const int wn = (w >> 1) * 32;          // N-half of this wave

  f32x4 acc[2];
#pragma unroll
  for (int j = 0; j < 2; ++j) acc[j] = (f32x4){0.f, 0.f, 0.f, 0.f};

  float xv[8];
  float bv[16];

#define LOADX(KK)                                                              \
  _Pragma("unroll")                                                            \
  for (int j = 0; j < 8; ++j)                                                  \
    xv[j] = X[(size_t)(k0 + (KK) + w * 16 + hi * 8 + j) * LSEQ + t0 + tl];

#define LOADB(KK)                                                              \
  _Pragma("unroll")                                                            \
  for (int p = 0; p < 2; ++p) {                                                \
    int n = p * 32 + w * 8 + brow;                                             \
    float4 f0 = *(const float4*)&B[(size_t)n * D_CH + k0 + (KK) + bkc];        \
    float4 f1 = *(const float4*)&B[(size_t)n * D_CH + k0 + (KK) + bkc + 4];    \
    bv[p * 8 + 0] = f0.x; bv[p * 8 + 1] = f0.y;                                \
    bv[p * 8 + 2] = f0.z; bv[p * 8 + 3] = f0.w;                                \
    bv[p * 8 + 4] = f1.x; bv[p * 8 + 5] = f1.y;                                \
    bv[p * 8 + 6] = f1.z; bv[p * 8 + 7] = f1.w;                                \
  }

  LOADX(0)
  LOADB(0)

  for (int kk = 0; kk < KS; kk += 64) {
    // cvt + LDS write of the tile staged in registers
    bf16x8 xp;
#pragma unroll
    for (int j = 0; j < 8; ++j) xp[j] = f2bf(xv[j]);
    *(bf16x8*)&Xs[tl * 72 + w * 16 + hi * 8] = xp;
#pragma unroll
    for (int p = 0; p < 2; ++p) {
      bf16x8 bp8;
#pragma unroll
      for (int j = 0; j < 8; ++j) bp8[j] = f2bf(bv[p * 8 + j]);
      *(bf16x8*)&Bs[(p * 32 + w * 8 + brow) * 72 + bkc] = bp8;
    }
    __syncthreads();

    // prefetch next K-step into registers (overlaps MFMA + barrier)
    if (kk + 64 < KS) {
      LOADX(kk + 64)
      LOADB(kk + 64)
    }

#pragma unroll
    for (int ks = 0; ks < 64; ks += 32) {
      bf16x8 a = *(const bf16x8*)&Xs[(wm + r) * 72 + ks + q * 8];
#pragma unroll
      for (int j = 0; j < 2; ++j) {
        bf16x8 bb = *(const bf16x8*)&Bs[(wn + j * 16 + r) * 72 + ks + q * 8];
        acc[j] = __builtin_amdgcn_mfma_f32_16x16x32_bf16(a, bb, acc[j], 0, 0, 0);
      }
    }
    __syncthreads();
  }
#undef LOADX
#undef LOADB

  float* Vs = V + (size_t)slab * VSLAB;
#pragma unroll
  for (int j = 0; j < 2; ++j)
#pragma unroll
    for (int reg = 0; reg < 4; ++reg)
      Vs[(size_t)(t0 + wm + q * 4 + reg) * 64 + wn + j * 16 + r] = acc[j][reg];
}

// ---------------------------------------------------------------------------
// matvec step: h' = M h + u, h broadcast via LDS ping-pong
// ---------------------------------------------------------------------------
__device__ __forceinline__ float matvec(const float ar[64], const float* __restrict__ hb,
                                        float u) {
  float a0 = u, a1 = 0.f, a2 = 0.f, a3 = 0.f;
#pragma unroll
  for (int jj = 0; jj < 64; jj += 4) {
    float4 hv = *(const float4*)&hb[jj];
    a0 += ar[jj + 0] * hv.x;
    a1 += ar[jj + 1] * hv.y;
    a2 += ar[jj + 2] * hv.z;
    a3 += ar[jj + 3] * hv.w;
  }
  return (a0 + a1) + (a2 + a3);
}

// ---------------------------------------------------------------------------
// scan1: blocks 0..NC1-1: U-chunk = invd applied to sum of V slabs, then
// wave 0 does the serial 32-step chunk summary.
// block NC1: 9 fp32 squarings of dA -> dA^32, dA^512 (for mid, next launch).
// ---------------------------------------------------------------------------
__global__ __launch_bounds__(256) void scan1_kernel(const float* __restrict__ V,
                                                    const float* __restrict__ invdT,
                                                    const float* __restrict__ dA,
                                                    float* __restrict__ U,
                                                    float* __restrict__ S,
                                                    float* __restrict__ dA32g,
                                                    float* __restrict__ dA512g,
                                                    int nslab) {
  __shared__ float smem[8704];
  const int tid = threadIdx.x;
  const int c = blockIdx.x;

  if (c == NC1) {
    // fp32 squaring chain (numerically critical — see header comment)
    float* b0 = smem;
    float* b1 = smem + 4352;
    const int r0 = (tid >> 4) * 4, c0 = (tid & 15) * 4;
    for (int idx = tid; idx < 4096; idx += 256)
      b0[(idx >> 6) * 68 + (idx & 63)] = dA[idx];
    __syncthreads();
    float acc[16];
    float* p = b0; float* q = b1;
    for (int s = 1; s <= 9; ++s) {
      mmzero(acc); mac44<68, 68>(acc, p, p, r0, c0);
      if (s == 5) mmst<64>(dA32g, acc, r0, c0);
      if (s == 9) mmst<64>(dA512g, acc, r0, c0);
      mmst<68>(q, acc, r0, c0);
      __syncthreads();
      float* t = p; p = q; q = t;
    }
    return;
  }

  float* invs = smem;            // 4096
  float* Vs   = smem + 4096;     // 2048
  float* Us   = smem + 6144;     // 2048
  float* hs0  = smem + 8192;     // 64
  float* hs1  = smem + 8256;     // 64

  for (int idx = tid; idx < 4096; idx += 256) invs[idx] = invdT[idx];
  for (int idx = tid; idx < 2048; idx += 256) {
    float v = 0.f;
    for (int s = 0; s < nslab; ++s) v += V[(size_t)s * VSLAB + (size_t)c * 2048 + idx];
    Vs[idx] = v;
  }
  __syncthreads();

  // transform: 2 rows x 4 cols per thread
  const int r0 = (tid >> 4) * 2, c0 = (tid & 15) * 4;
  float a0[4] = {0.f, 0.f, 0.f, 0.f}, a1[4] = {0.f, 0.f, 0.f, 0.f};
#pragma unroll 4
  for (int k = 0; k < 64; k += 4) {
    float4 v0 = *(const float4*)&Vs[r0 * 64 + k];
    float4 v1 = *(const float4*)&Vs[(r0 + 1) * 64 + k];
    float4 y0 = *(const float4*)&invs[(k + 0) * 64 + c0];
    float4 y1 = *(const float4*)&invs[(k + 1) * 64 + c0];
    float4 y2 = *(const float4*)&invs[(k + 2) * 64 + c0];
    float4 y3 = *(const float4*)&invs[(k + 3) * 64 + c0];
    a0[0] += v0.x * y0.x + v0.y * y1.x + v0.z * y2.x + v0.w * y3.x;
    a0[1] += v0.x * y0.y + v0.y * y1.y + v0.z * y2.y + v0.w * y3.y;
    a0[2] += v0.x * y0.z + v0.y * y1.z + v0.z * y2.z + v0.w * y3.z;
    a0[3] += v0.x * y0.w + v0.y * y1.w + v0.z * y2.w + v0.w * y3.w;
    a1[0] += v1.x * y0.x + v1.y * y1.x + v1.z * y2.x + v1.w * y3.x;
    a1[1] += v1.x * y0.y + v1.y * y1.y + v1.z * y2.y + v1.w * y3.y;
    a1[2] += v1.x * y0.z + v1.y * y1.z + v1.z * y2.z + v1.w * y3.z;
    a1[3] += v1.x * y0.w + v1.y * y1.w + v1.z * y2.w + v1.w * y3.w;
  }
  *(float4*)&Us[r0 * 64 + c0] = make_float4(a0[0], a0[1], a0[2], a0[3]);
  *(float4*)&Us[(r0 + 1) * 64 + c0] = make_float4(a1[0], a1[1], a1[2], a1[3]);
  *(float4*)&U[(size_t)(c * 32 + r0) * 64 + c0] = make_float4(a0[0], a0[1], a0[2], a0[3]);
  *(float4*)&U[(size_t)(c * 32 + r0 + 1) * 64 + c0] = make_float4(a1[0], a1[1], a1[2], a1[3]);
  __syncthreads();

  if (tid < 64) {
    float ar[64];
#pragma unroll
    for (int jj = 0; jj < 64; jj += 4) {
      float4 v = *(const float4*)&dA[tid * 64 + jj];
      ar[jj] = v.x; ar[jj + 1] = v.y; ar[jj + 2] = v.z; ar[jj + 3] = v.w;
    }
    float h = 0.f;
    hs0[tid] = 0.f;
    for (int t = 0; t < T1; ++t) {
      float u = Us[t * 64 + tid];
      h = matvec(ar, (t & 1) ? hs1 : hs0, u);
      ((t & 1) ? hs0 : hs1)[tid] = h;
    }
    S[c * 64 + tid] = h;
  }
}

// ---------------------------------------------------------------------------
// mid: 3 middle levels in one block (16 waves), round-4 proven.
// Register budget: the block has exactly 1 instance in the grid, so runtime
// occupancy is fixed at 4 waves/EU regardless of VGPR count.
// __launch_bounds__'s 2nd arg is a MIN waves/EU (can only LOWER the budget),
// so it left the allocator at its 8-waves/EU default = 64 VGPRs, spilling
// ar[64] (measured r1/r2: VGPR_Count=64, ~51 us latency chain).
// amdgpu_waves_per_eu(4,4) pins max waves/EU = 4 -> budget 512/4 = 128
// VGPRs -> ar[64] stays in registers.
// ---------------------------------------------------------------------------
__global__ __launch_bounds__(1024)
__attribute__((amdgpu_waves_per_eu(4, 4))) void mid_kernel(
    const float* __restrict__ S, const float* __restrict__ dA32,
    const float* __restrict__ dA512, float* __restrict__ Hinit) {
  __shared__ float S2s[1024];
  __shared__ float H2s[1024];
  __shared__ float hsbuf[2048];
  const int tid = threadIdx.x;
  const int wave = tid >> 6, lane = tid & 63;
  float* hs0 = &hsbuf[wave * 128];
  float* hs1 = hs0 + 64;
  const float* inw = S + wave * 16 * 64;

  // ---- phase 1: 16 parallel 16-step scans with dA32 ----
  {
    float ar[64];
#pragma unroll
    for (int jj = 0; jj < 64; jj += 4) {
      float4 v = *(const float4*)&dA32[lane * 64 + jj];
      ar[jj] = v.x; ar[jj + 1] = v.y; ar[jj + 2] = v.z; ar[jj + 3] = v.w;
    }
    float h = 0.f;
    hs0[lane] = 0.f;
    for (int t = 0; t < 16; ++t) {
      float u = inw[t * 64 + lane];
      h = matvec(ar, (t & 1) ? hs1 : hs0, u);
      ((t & 1) ? hs0 : hs1)[lane] = h;
    }
    S2s[wave * 64 + lane] = h;
  }
  __syncthreads();

  // ---- phase 2: wave 0 scans the 16 summaries with dA512 ----
  if (wave == 0) {
    float br[64];
#pragma unroll
    for (int jj = 0; jj < 64; jj += 4) {
      float4 v = *(const float4*)&dA512[lane * 64 + jj];
      br[jj] = v.x; br[jj + 1] = v.y; br[jj + 2] = v.z; br[jj + 3] = v.w;
    }
    float g = 0.f;
    hs0[lane] = 0.f;
    for (int t = 0; t < 16; ++t) {
      H2s[t * 64 + lane] = g;
      float u = S2s[t * 64 + lane];
      g = matvec(br, (t & 1) ? hs1 : hs0, u);
      ((t & 1) ? hs0 : hs1)[lane] = g;
    }
  }
  __syncthreads();

  // ---- phase 3: re-expand with dA32 (ar reloaded; L2-warm) ----
  {
    float ar[64];
#pragma unroll
    for (int jj = 0; jj < 64; jj += 4) {
      float4 v = *(const float4*)&dA32[lane * 64 + jj];
      ar[jj] = v.x; ar[jj + 1] = v.y; ar[jj + 2] = v.z; ar[jj + 3] = v.w;
    }
    float h = H2s[wave * 64 + lane];
    hs0[lane] = h;
    for (int t = 0; t < 16; ++t) {
      Hinit[(wave * 16 + t) * 64 + lane] = h;
      float u = inw[t * 64 + lane];
      h = matvec(ar, (t & 1) ? hs1 : hs0, u);
      ((t & 1) ? hs0 : hs1)[lane] = h;
    }
  }
}

// ---------------------------------------------------------------------------
// scan2: one wave/block, full-state expansion with 4-deep prefetch ring.
// ---------------------------------------------------------------------------
__global__ __launch_bounds__(64) void scan2_kernel(const float* __restrict__ U,
                                                   const float* __restrict__ dA,
                                                   const float* __restrict__ Hinit,
                                                   float* __restrict__ Ht) {
  __shared__ float hs[2][64];
  const int tid = threadIdx.x;
  const int c = blockIdx.x;
  float ar[64];
#pragma unroll
  for (int jj = 0; jj < 64; jj += 4) {
    float4 v = *(const float4*)&dA[tid * 64 + jj];
    ar[jj] = v.x; ar[jj + 1] = v.y; ar[jj + 2] = v.z; ar[jj + 3] = v.w;
  }
  float h = Hinit[c * 64 + tid];
  hs[0][tid] = h;
  const float* inc = U + (size_t)c * T1 * 64;
  float* outc = Ht + (size_t)c * T1 * 64;
  float up[4];
#pragma unroll
  for (int i = 0; i < 4; ++i) up[i] = inc[i * 64 + tid];

  for (int t = 0; t < T1; ++t) {
    float u = up[t & 3];
    if (t + 4 < T1) up[t & 3] = inc[(t + 4) * 64 + tid];
    h = matvec(ar, hs[t & 1], u);
    hs[(t + 1) & 1][tid] = h;
    outc[t * 64 + tid] = h;
  }
}

// ---------------------------------------------------------------------------
// out: Y[d][t] = (C @ Ht^T)[d][t] + Dp[d]*X[d][t]  via bf16 MFMA (K = 64).
// ---------------------------------------------------------------------------
__global__ __launch_bounds__(256) void out_kernel(const float* __restrict__ X,
                                                  const float* __restrict__ C,
                                                  const float* __restrict__ Dp,
                                                  const float* __restrict__ Ht,
                                                  float* __restrict__ Y) {
  __shared__ short Cs[64 * 72];      // [d][n] bf16
  __shared__ short Hs[64 * 72];      // [t][n] bf16
  const int tid = threadIdx.x;
  const int lane = tid & 63, w = tid >> 6;
  const int t0 = blockIdx.x * 64;
  const int d0 = blockIdx.y * 64;
  const int q = lane >> 4, r = lane & 15;
  const int brow = lane >> 3, bkc = (lane & 7) * 8;

#pragma unroll
  for (int p = 0; p < 2; ++p) {
    int row = p * 32 + w * 8 + brow;
    float4 c0 = *(const float4*)&C[(size_t)(d0 + row) * 64 + bkc];
    float4 c1 = *(const float4*)&C[(size_t)(d0 + row) * 64 + bkc + 4];
    float4 h0 = *(const float4*)&Ht[(size_t)(t0 + row) * 64 + bkc];
    float4 h1 = *(const float4*)&Ht[(size_t)(t0 + row) * 64 + bkc + 4];
    bf16x8 cv, hv;
    cv[0] = f2bf(c0.x); cv[1] = f2bf(c0.y); cv[2] = f2bf(c0.z); cv[3] = f2bf(c0.w);
    cv[4] = f2bf(c1.x); cv[5] = f2bf(c1.y); cv[6] = f2bf(c1.z); cv[7] = f2bf(c1.w);
    hv[0] = f2bf(h0.x); hv[1] = f2bf(h0.y); hv[2] = f2bf(h0.z); hv[3] = f2bf(h0.w);
    hv[4] = f2bf(h1.x); hv[5] = f2bf(h1.y); hv[6] = f2bf(h1.z); hv[7] = f2bf(h1.w);
    *(bf16x8*)&Cs[row * 72 + bkc] = cv;
    *(bf16x8*)&Hs[row * 72 + bkc] = hv;
  }
  __syncthreads();

  f32x4 acc[4];
#pragma unroll
  for (int j = 0; j < 4; ++j) acc[j] = (f32x4){0.f, 0.f, 0.f, 0.f};
#pragma unroll
  for (int ks = 0; ks < 64; ks += 32) {
    bf16x8 a = *(const bf16x8*)&Cs[(w * 16 + r) * 72 + ks + q * 8];
#pragma unroll
    for (int j = 0; j < 4; ++j) {
      bf16x8 bb = *(const bf16x8*)&Hs[(j * 16 + r) * 72 + ks + q * 8];
      acc[j] = __builtin_amdgcn_mfma_f32_16x16x32_bf16(a, bb, acc[j], 0, 0, 0);
    }
  }

#pragma unroll
  for (int reg = 0; reg < 4; ++reg) {
    int d = d0 + w * 16 + q * 4 + reg;
    float dp = Dp[d];
#pragma unroll
    for (int j = 0; j < 4; ++j) {
      int t = t0 + j * 16 + r;
      size_t off = (size_t)d * LSEQ + t;
      Y[off] = acc[j][reg] + dp * X[off];
    }
  }
}

// ---------------------------------------------------------------------------
extern "C" void kernel_launch(void* const* d_in, const int* in_sizes, int n_in,
                              void* d_out, int out_size, void* d_ws, size_t ws_size,
                              hipStream_t stream) {
  const float* X  = (const float*)d_in[0];
  const float* A  = (const float*)d_in[1];
  const float* B  = (const float*)d_in[2];
  const float* Cm = (const float*)d_in[3];
  const float* Dp = (const float*)d_in[4];
  const float* ld = (const float*)d_in[5];
  float* out = (float*)d_out;
  float* ws = (float*)d_ws;

  // 4 K-slabs if workspace allows (10.2 MB), else 2 (6.2 MB)
  const size_t need4 = (size_t)(16384 + 4 * VSLAB + VSLAB + 16384 + 16384) * 4;
  const int nslab = (ws_size >= need4) ? 4 : 2;

  float* invdT = ws;                       // 4096
  float* dA    = ws + 4096;                // 4096
  float* dA32  = ws + 8192;                // 4096
  float* dA512 = ws + 12288;               // 4096
  float* V     = ws + 16384;               // nslab * 524288
  float* U     = V + (size_t)nslab * VSLAB; // 524288
  float* S     = U + VSLAB;                // 16384
  float* Hinit = S + 16384;                // 16384
  float* Ht    = V;                         // overlay: V dead after scan1

  main_kernel<<<nslab * 256 + 1, 256, 0, stream>>>(X, A, B, ld, invdT, dA, V,
                                                   2048 / nslab);
  scan1_kernel<<<NC1 + 1, 256, 0, stream>>>(V, invdT, dA, U, S, dA32, dA512, nslab);
  mid_kernel<<<1, 1024, 0, stream>>>(S, dA32, dA512, Hinit);
  scan2_kernel<<<NC1, 64, 0, stream>>>(U, dA, Hinit, Ht);
  out_kernel<<<dim3(128, 32), 256, 0, stream>>>(X, Cm, Dp, Ht, out);
}

// Round 4
// 223.122 us; speedup vs baseline: 1.1521x; 1.1423x over previous
//
#include <hip/hip_runtime.h>
#include <math.h>

#define D_CH 2048
#define LSEQ 8192
#define T1 32
#define NC1 256          // LSEQ / T1
#define VSLAB 524288     // per-slab V floats (8192*64)

typedef __attribute__((ext_vector_type(8))) short bf16x8;
typedef __attribute__((ext_vector_type(4))) float f32x4;

__device__ __forceinline__ short f2bf(float x) {
  unsigned u = __float_as_uint(x);
  u += 0x7FFFu + ((u >> 16) & 1);       // round-to-nearest-even
  return (short)(u >> 16);
}

// ---------------------------------------------------------------------------
// fp32 4x4-register-tile 64x64 matmul helpers on LDS (numerically critical
// dA-power chain stays fp32: squaring DOUBLES relative exponent error, so
// bf16 squarings diverge — measured round 5: 65% output error).
// ---------------------------------------------------------------------------
__device__ __forceinline__ void mmzero(float acc[16]) {
#pragma unroll
  for (int t = 0; t < 16; ++t) acc[t] = 0.f;
}

template <int SZ>
__device__ __forceinline__ void mmld(float acc[16], const float* __restrict__ Z,
                                     int r0, int c0) {
#pragma unroll
  for (int i = 0; i < 4; ++i) {
    float4 z = *(const float4*)&Z[(r0 + i) * SZ + c0];
    acc[i * 4 + 0] = z.x; acc[i * 4 + 1] = z.y;
    acc[i * 4 + 2] = z.z; acc[i * 4 + 3] = z.w;
  }
}

template <int SX, int SY>
__device__ __forceinline__ void mac44(float acc[16], const float* __restrict__ Xb,
                                      const float* __restrict__ Yb, int r0, int c0) {
#pragma unroll 4
  for (int k = 0; k < 64; k += 4) {
    float4 x0 = *(const float4*)&Xb[(r0 + 0) * SX + k];
    float4 x1 = *(const float4*)&Xb[(r0 + 1) * SX + k];
    float4 x2 = *(const float4*)&Xb[(r0 + 2) * SX + k];
    float4 x3 = *(const float4*)&Xb[(r0 + 3) * SX + k];
    float4 y0 = *(const float4*)&Yb[(k + 0) * SY + c0];
    float4 y1 = *(const float4*)&Yb[(k + 1) * SY + c0];
    float4 y2 = *(const float4*)&Yb[(k + 2) * SY + c0];
    float4 y3 = *(const float4*)&Yb[(k + 3) * SY + c0];
#define MROW(i, xi) \
    acc[i * 4 + 0] += xi.x * y0.x + xi.y * y1.x + xi.z * y2.x + xi.w * y3.x; \
    acc[i * 4 + 1] += xi.x * y0.y + xi.y * y1.y + xi.z * y2.y + xi.w * y3.y; \
    acc[i * 4 + 2] += xi.x * y0.z + xi.y * y1.z + xi.z * y2.z + xi.w * y3.z; \
    acc[i * 4 + 3] += xi.x * y0.w + xi.y * y1.w + xi.z * y2.w + xi.w * y3.w;
    MROW(0, x0) MROW(1, x1) MROW(2, x2) MROW(3, x3)
#undef MROW
  }
}

template <int SZ>
__device__ __forceinline__ void mmst(float* Dst, const float acc[16], int r0, int c0) {
#pragma unroll
  for (int i = 0; i < 4; ++i)
    *(float4*)&Dst[(r0 + i) * SZ + c0] =
        make_float4(acc[i * 4 + 0], acc[i * 4 + 1], acc[i * 4 + 2], acc[i * 4 + 3]);
}

// ---------------------------------------------------------------------------
// main_kernel:
//   block 0: prep — fp32 Q-chain (2-buffer, register-held step products)
//            -> invdT (delta*Q^T), dA = 2Q-I
//   blocks 1..: V[slab] = B @ X  (bf16 MFMA, 32t x 64n tiles, K-slab,
//            register prefetch of next K-step).
// ---------------------------------------------------------------------------
__global__ __launch_bounds__(256) void main_kernel(const float* __restrict__ X,
                                                   const float* __restrict__ A,
                                                   const float* __restrict__ B,
                                                   const float* __restrict__ logd,
                                                   float* __restrict__ invdT,
                                                   float* __restrict__ dAg,
                                                   float* __restrict__ V,
                                                   int KS) {
  __shared__ float smem[8704];           // 34.8 KB union
  const int tid = threadIdx.x;
  const int lane = tid & 63;
  const int w = tid >> 6;

  if (blockIdx.x == 0) {
    // ---------------- Q-chain (fp32): Q ~= inv(I - P), ||P|| <= ~0.12 ------
    float* bQ = smem;
    float* bP = smem + 4352;
    const int r0 = (tid >> 4) * 4, c0 = (tid & 15) * 4;
    const float delta = expf(logd[0]);
    const float half = 0.5f * delta;
    float accQ[16], accP[16];

    for (int idx = tid; idx < 4096; idx += 256) {
      int i = idx >> 6, j = idx & 63;
      float p = half * A[idx];
      bP[i * 68 + j] = p;
      bQ[i * 68 + j] = p + (i == j ? 1.f : 0.f);   // S2 = I + P
    }
    __syncthreads();
    // bP = P^2
    mmzero(accP); mac44<68, 68>(accP, bP, bP, r0, c0);
    __syncthreads();
    mmst<68>(bP, accP, r0, c0);
    __syncthreads();
#pragma unroll 1
    for (int s = 0; s < 3; ++s) {
      mmld<68>(accQ, bQ, r0, c0);
      mac44<68, 68>(accQ, bP, bQ, r0, c0);        // Q + P^k * Q
      if (s < 2) { mmzero(accP); mac44<68, 68>(accP, bP, bP, r0, c0); }
      __syncthreads();
      mmst<68>(bQ, accQ, r0, c0);
      if (s < 2) mmst<68>(bP, accP, r0, c0);
      __syncthreads();
    }

    // exports: invdT = delta*Q^T, dA = 2Q - I
    for (int idx = tid; idx < 4096; idx += 256) {
      int n = idx >> 6, m = idx & 63;
      float qv = bQ[n * 68 + m];
      invdT[m * 64 + n] = delta * qv;
      dAg[idx] = 2.f * qv - (n == m ? 1.f : 0.f);
    }
    return;
  }

  // ------------------------------ vgemm (bf16 MFMA) ------------------------
  const int b = blockIdx.x - 1;
  const int t0 = (b & 255) << 5;         // 256 t-tiles of 32
  const int slab = b >> 8;
  const int k0 = slab * KS;
  short* Xs = (short*)smem;              // [32][72] bf16  (t-major)
  short* Bs = (short*)smem + 2304;       // [64][72] bf16  (n-major)
  const int q = lane >> 4, r = lane & 15;
  const int hi = lane >> 5, tl = lane & 31;
  const int brow = lane >> 3;            // 0..7
  const int bkc = (lane & 7) * 8;        // 0..56
  const int wm = (w & 1) * 16;           // M-half of this wave
  const int wn = (w >> 1) * 32;          // N-half of this wave

  f32x4 acc[2];
#pragma unroll
  for (int j = 0; j < 2; ++j) acc[j] = (f32x4){0.f, 0.f, 0.f, 0.f};

  float xv[8];
  float bv[16];

#define LOADX(KK)                                                              \
  _Pragma("unroll")                                                            \
  for (int j = 0; j < 8; ++j)                                                  \
    xv[j] = X[(size_t)(k0 + (KK) + w * 16 + hi * 8 + j) * LSEQ + t0 + tl];

#define LOADB(KK)                                                              \
  _Pragma("unroll")                                                            \
  for (int p = 0; p < 2; ++p) {                                                \
    int n = p * 32 + w * 8 + brow;                                             \
    float4 f0 = *(const float4*)&B[(size_t)n * D_CH + k0 + (KK) + bkc];        \
    float4 f1 = *(const float4*)&B[(size_t)n * D_CH + k0 + (KK) + bkc + 4];    \
    bv[p * 8 + 0] = f0.x; bv[p * 8 + 1] = f0.y;                                \
    bv[p * 8 + 2] = f0.z; bv[p * 8 + 3] = f0.w;                                \
    bv[p * 8 + 4] = f1.x; bv[p * 8 + 5] = f1.y;                                \
    bv[p * 8 + 6] = f1.z; bv[p * 8 + 7] = f1.w;                                \
  }

  LOADX(0)
  LOADB(0)

  for (int kk = 0; kk < KS; kk += 64) {
    bf16x8 xp;
#pragma unroll
    for (int j = 0; j < 8; ++j) xp[j] = f2bf(xv[j]);
    *(bf16x8*)&Xs[tl * 72 + w * 16 + hi * 8] = xp;
#pragma unroll
    for (int p = 0; p < 2; ++p) {
      bf16x8 bp8;
#pragma unroll
      for (int j = 0; j < 8; ++j) bp8[j] = f2bf(bv[p * 8 + j]);
      *(bf16x8*)&Bs[(p * 32 + w * 8 + brow) * 72 + bkc] = bp8;
    }
    __syncthreads();

    if (kk + 64 < KS) {
      LOADX(kk + 64)
      LOADB(kk + 64)
    }

#pragma unroll
    for (int ks = 0; ks < 64; ks += 32) {
      bf16x8 a = *(const bf16x8*)&Xs[(wm + r) * 72 + ks + q * 8];
#pragma unroll
      for (int j = 0; j < 2; ++j) {
        bf16x8 bb = *(const bf16x8*)&Bs[(wn + j * 16 + r) * 72 + ks + q * 8];
        acc[j] = __builtin_amdgcn_mfma_f32_16x16x32_bf16(a, bb, acc[j], 0, 0, 0);
      }
    }
    __syncthreads();
  }
#undef LOADX
#undef LOADB

  float* Vs = V + (size_t)slab * VSLAB;
#pragma unroll
  for (int j = 0; j < 2; ++j)
#pragma unroll
    for (int reg = 0; reg < 4; ++reg)
      Vs[(size_t)(t0 + wm + q * 4 + reg) * 64 + wn + j * 16 + r] = acc[j][reg];
}

// ---------------------------------------------------------------------------
// LDS-resident matvec: h'[lane] = u + M[lane][:] . hb[:]
// M stored with stride 68 -> bank (4*row+col)%32: a wave's 64 ds_read_b128
// row reads spread across all 8 four-bank groups = structural floor (no
// conflict); hb reads are same-address broadcasts (free).  This pattern is
// allocator-proof: rounds 1-3 proved the compiler refuses to keep a 64-float
// per-lane matrix row in VGPRs (VGPR_Count pinned at 64; it re-loads the row
// from L2 inside the serial loop -> ~2400 cy/step, 47 us for mid).
// ---------------------------------------------------------------------------
__device__ __forceinline__ float matvec_lds(const float* __restrict__ Mrow,
                                            const float* __restrict__ hb, float u) {
  float a0 = u, a1 = 0.f, a2 = 0.f, a3 = 0.f;
#pragma unroll
  for (int jj = 0; jj < 64; jj += 4) {
    float4 m = *(const float4*)&Mrow[jj];
    float4 hv = *(const float4*)&hb[jj];
    a0 += m.x * hv.x;
    a1 += m.y * hv.y;
    a2 += m.z * hv.z;
    a3 += m.w * hv.w;
  }
  return (a0 + a1) + (a2 + a3);
}

// stage a 64x64 fp32 matrix into [64][68]-padded LDS, 64-thread block,
// coalesced 1 KB per iteration.
__device__ __forceinline__ void stage_mat64(float* Mlds, const float* __restrict__ Mg,
                                            int lane) {
#pragma unroll
  for (int i = 0; i < 16; ++i) {
    int row = i * 4 + (lane >> 4);
    int col = (lane & 15) * 4;
    *(float4*)&Mlds[row * 68 + col] = *(const float4*)&Mg[row * 64 + col];
  }
  __syncthreads();
}

// ---------------------------------------------------------------------------
// scan1: blocks 0..NC1-1: U-chunk = invd applied to sum of V slabs, then
// wave 0 does the serial 32-step chunk summary (dA staged in padded LDS).
// block NC1: 9 fp32 squarings of dA -> dA^32, dA^512.
// ---------------------------------------------------------------------------
__global__ __launch_bounds__(256) void scan1_kernel(const float* __restrict__ V,
                                                    const float* __restrict__ invdT,
                                                    const float* __restrict__ dA,
                                                    float* __restrict__ U,
                                                    float* __restrict__ S,
                                                    float* __restrict__ dA32g,
                                                    float* __restrict__ dA512g,
                                                    int nslab) {
  __shared__ float smem[13056];
  const int tid = threadIdx.x;
  const int c = blockIdx.x;

  if (c == NC1) {
    // fp32 squaring chain (numerically critical — see header comment)
    float* b0 = smem;
    float* b1 = smem + 4352;
    const int r0 = (tid >> 4) * 4, c0 = (tid & 15) * 4;
    for (int idx = tid; idx < 4096; idx += 256)
      b0[(idx >> 6) * 68 + (idx & 63)] = dA[idx];
    __syncthreads();
    float acc[16];
    float* p = b0; float* q = b1;
    for (int s = 1; s <= 9; ++s) {
      mmzero(acc); mac44<68, 68>(acc, p, p, r0, c0);
      if (s == 5) mmst<64>(dA32g, acc, r0, c0);
      if (s == 9) mmst<64>(dA512g, acc, r0, c0);
      mmst<68>(q, acc, r0, c0);
      __syncthreads();
      float* t = p; p = q; q = t;
    }
    return;
  }

  float* invs = smem;            // 4096
  float* Vs   = smem + 4096;     // 2048
  float* Us   = smem + 6144;     // 2048
  float* hs0  = smem + 8192;     // 64
  float* hs1  = smem + 8256;     // 64
  float* Md   = smem + 8320;     // 4352 ([64][68] padded dA)

  for (int idx = tid; idx < 4096; idx += 256) invs[idx] = invdT[idx];
  for (int idx = tid; idx < 4096; idx += 256)
    Md[(idx >> 6) * 68 + (idx & 63)] = dA[idx];
  for (int idx = tid; idx < 2048; idx += 256) {
    float v = 0.f;
    for (int s = 0; s < nslab; ++s) v += V[(size_t)s * VSLAB + (size_t)c * 2048 + idx];
    Vs[idx] = v;
  }
  __syncthreads();

  // transform: 2 rows x 4 cols per thread
  const int r0 = (tid >> 4) * 2, c0 = (tid & 15) * 4;
  float a0[4] = {0.f, 0.f, 0.f, 0.f}, a1[4] = {0.f, 0.f, 0.f, 0.f};
#pragma unroll 4
  for (int k = 0; k < 64; k += 4) {
    float4 v0 = *(const float4*)&Vs[r0 * 64 + k];
    float4 v1 = *(const float4*)&Vs[(r0 + 1) * 64 + k];
    float4 y0 = *(const float4*)&invs[(k + 0) * 64 + c0];
    float4 y1 = *(const float4*)&invs[(k + 1) * 64 + c0];
    float4 y2 = *(const float4*)&invs[(k + 2) * 64 + c0];
    float4 y3 = *(const float4*)&invs[(k + 3) * 64 + c0];
    a0[0] += v0.x * y0.x + v0.y * y1.x + v0.z * y2.x + v0.w * y3.x;
    a0[1] += v0.x * y0.y + v0.y * y1.y + v0.z * y2.y + v0.w * y3.y;
    a0[2] += v0.x * y0.z + v0.y * y1.z + v0.z * y2.z + v0.w * y3.z;
    a0[3] += v0.x * y0.w + v0.y * y1.w + v0.z * y2.w + v0.w * y3.w;
    a1[0] += v1.x * y0.x + v1.y * y1.x + v1.z * y2.x + v1.w * y3.x;
    a1[1] += v1.x * y0.y + v1.y * y1.y + v1.z * y2.y + v1.w * y3.y;
    a1[2] += v1.x * y0.z + v1.y * y1.z + v1.z * y2.z + v1.w * y3.z;
    a1[3] += v1.x * y0.w + v1.y * y1.w + v1.z * y2.w + v1.w * y3.w;
  }
  *(float4*)&Us[r0 * 64 + c0] = make_float4(a0[0], a0[1], a0[2], a0[3]);
  *(float4*)&Us[(r0 + 1) * 64 + c0] = make_float4(a1[0], a1[1], a1[2], a1[3]);
  *(float4*)&U[(size_t)(c * 32 + r0) * 64 + c0] = make_float4(a0[0], a0[1], a0[2], a0[3]);
  *(float4*)&U[(size_t)(c * 32 + r0 + 1) * 64 + c0] = make_float4(a1[0], a1[1], a1[2], a1[3]);
  __syncthreads();

  if (tid < 64) {
    const float* row = Md + tid * 68;
    float h = 0.f;
    hs0[tid] = 0.f;
    for (int t = 0; t < T1; ++t) {
      float u = Us[t * 64 + tid];
      h = matvec_lds(row, (t & 1) ? hs1 : hs0, u);
      ((t & 1) ? hs0 : hs1)[tid] = h;
    }
    S[c * 64 + tid] = h;
  }
}

// ---------------------------------------------------------------------------
// mid stage, split into 3 one-wave-per-block kernels so each scan wave owns
// a full CU's LDS bandwidth (the old single-block 16-wave mid_kernel was a
// 47.6 us latency chain).  Identical fp32 arithmetic / accumulation order.
// ---------------------------------------------------------------------------
// mid1: block g scans S[g*16..g*16+15] with dA32 -> S2g[g]
__global__ __launch_bounds__(64) void mid1_kernel(const float* __restrict__ S,
                                                  const float* __restrict__ dA32,
                                                  float* __restrict__ S2g) {
  __shared__ float M[64 * 68];
  __shared__ float hs[2][64];
  const int lane = threadIdx.x;
  const int g = blockIdx.x;
  stage_mat64(M, dA32, lane);
  const float* row = M + lane * 68;
  const float* in = S + g * 16 * 64;
  float h = 0.f;
  hs[0][lane] = 0.f;
  for (int t = 0; t < 16; ++t) {
    h = matvec_lds(row, hs[t & 1], in[t * 64 + lane]);
    hs[(t + 1) & 1][lane] = h;
  }
  S2g[g * 64 + lane] = h;
}

// mid2: exclusive scan of the 16 group summaries with dA512 -> H2g
__global__ __launch_bounds__(64) void mid2_kernel(const float* __restrict__ S2g,
                                                  const float* __restrict__ dA512,
                                                  float* __restrict__ H2g) {
  __shared__ float M[64 * 68];
  __shared__ float hs[2][64];
  const int lane = threadIdx.x;
  stage_mat64(M, dA512, lane);
  const float* row = M + lane * 68;
  float h = 0.f;
  hs[0][lane] = 0.f;
  for (int t = 0; t < 16; ++t) {
    H2g[t * 64 + lane] = h;
    h = matvec_lds(row, hs[t & 1], S2g[t * 64 + lane]);
    hs[(t + 1) & 1][lane] = h;
  }
}

// mid3: block g re-expands group g: Hinit[g*16+t] for t = 0..15
__global__ __launch_bounds__(64) void mid3_kernel(const float* __restrict__ S,
                                                  const float* __restrict__ dA32,
                                                  const float* __restrict__ H2g,
                                                  float* __restrict__ Hinit) {
  __shared__ float M[64 * 68];
  __shared__ float hs[2][64];
  const int lane = threadIdx.x;
  const int g = blockIdx.x;
  stage_mat64(M, dA32, lane);
  const float* row = M + lane * 68;
  const float* in = S + g * 16 * 64;
  float h = H2g[g * 64 + lane];
  hs[0][lane] = h;
  for (int t = 0; t < 16; ++t) {
    Hinit[(g * 16 + t) * 64 + lane] = h;
    h = matvec_lds(row, hs[t & 1], in[t * 64 + lane]);
    hs[(t + 1) & 1][lane] = h;
  }
}

// ---------------------------------------------------------------------------
// scan2: one wave/block, full-state expansion, dA staged in padded LDS,
// 4-deep prefetch ring on U.
// ---------------------------------------------------------------------------
__global__ __launch_bounds__(64) void scan2_kernel(const float* __restrict__ U,
                                                   const float* __restrict__ dA,
                                                   const float* __restrict__ Hinit,
                                                   float* __restrict__ Ht) {
  __shared__ float M[64 * 68];
  __shared__ float hs[2][64];
  const int tid = threadIdx.x;
  const int c = blockIdx.x;
  stage_mat64(M, dA, tid);
  const float* row = M + tid * 68;
  float h = Hinit[c * 64 + tid];
  hs[0][tid] = h;
  const float* inc = U + (size_t)c * T1 * 64;
  float* outc = Ht + (size_t)c * T1 * 64;
  float up[4];
#pragma unroll
  for (int i = 0; i < 4; ++i) up[i] = inc[i * 64 + tid];

  for (int t = 0; t < T1; ++t) {
    float u = up[t & 3];
    if (t + 4 < T1) up[t & 3] = inc[(t + 4) * 64 + tid];
    h = matvec_lds(row, hs[t & 1], u);
    hs[(t + 1) & 1][tid] = h;
    outc[t * 64 + tid] = h;
  }
}

// ---------------------------------------------------------------------------
// out: Y[d][t] = (C @ Ht^T)[d][t] + Dp[d]*X[d][t]  via bf16 MFMA (K = 64).
// ---------------------------------------------------------------------------
__global__ __launch_bounds__(256) void out_kernel(const float* __restrict__ X,
                                                  const float* __restrict__ C,
                                                  const float* __restrict__ Dp,
                                                  const float* __restrict__ Ht,
                                                  float* __restrict__ Y) {
  __shared__ short Cs[64 * 72];      // [d][n] bf16
  __shared__ short Hs[64 * 72];      // [t][n] bf16
  const int tid = threadIdx.x;
  const int lane = tid & 63, w = tid >> 6;
  const int t0 = blockIdx.x * 64;
  const int d0 = blockIdx.y * 64;
  const int q = lane >> 4, r = lane & 15;
  const int brow = lane >> 3, bkc = (lane & 7) * 8;

#pragma unroll
  for (int p = 0; p < 2; ++p) {
    int row = p * 32 + w * 8 + brow;
    float4 c0 = *(const float4*)&C[(size_t)(d0 + row) * 64 + bkc];
    float4 c1 = *(const float4*)&C[(size_t)(d0 + row) * 64 + bkc + 4];
    float4 h0 = *(const float4*)&Ht[(size_t)(t0 + row) * 64 + bkc];
    float4 h1 = *(const float4*)&Ht[(size_t)(t0 + row) * 64 + bkc + 4];
    bf16x8 cv, hv;
    cv[0] = f2bf(c0.x); cv[1] = f2bf(c0.y); cv[2] = f2bf(c0.z); cv[3] = f2bf(c0.w);
    cv[4] = f2bf(c1.x); cv[5] = f2bf(c1.y); cv[6] = f2bf(c1.z); cv[7] = f2bf(c1.w);
    hv[0] = f2bf(h0.x); hv[1] = f2bf(h0.y); hv[2] = f2bf(h0.z); hv[3] = f2bf(h0.w);
    hv[4] = f2bf(h1.x); hv[5] = f2bf(h1.y); hv[6] = f2bf(h1.z); hv[7] = f2bf(h1.w);
    *(bf16x8*)&Cs[row * 72 + bkc] = cv;
    *(bf16x8*)&Hs[row * 72 + bkc] = hv;
  }
  __syncthreads();

  f32x4 acc[4];
#pragma unroll
  for (int j = 0; j < 4; ++j) acc[j] = (f32x4){0.f, 0.f, 0.f, 0.f};
#pragma unroll
  for (int ks = 0; ks < 64; ks += 32) {
    bf16x8 a = *(const bf16x8*)&Cs[(w * 16 + r) * 72 + ks + q * 8];
#pragma unroll
    for (int j = 0; j < 4; ++j) {
      bf16x8 bb = *(const bf16x8*)&Hs[(j * 16 + r) * 72 + ks + q * 8];
      acc[j] = __builtin_amdgcn_mfma_f32_16x16x32_bf16(a, bb, acc[j], 0, 0, 0);
    }
  }

#pragma unroll
  for (int reg = 0; reg < 4; ++reg) {
    int d = d0 + w * 16 + q * 4 + reg;
    float dp = Dp[d];
#pragma unroll
    for (int j = 0; j < 4; ++j) {
      int t = t0 + j * 16 + r;
      size_t off = (size_t)d * LSEQ + t;
      Y[off] = acc[j][reg] + dp * X[off];
    }
  }
}

// ---------------------------------------------------------------------------
extern "C" void kernel_launch(void* const* d_in, const int* in_sizes, int n_in,
                              void* d_out, int out_size, void* d_ws, size_t ws_size,
                              hipStream_t stream) {
  const float* X  = (const float*)d_in[0];
  const float* A  = (const float*)d_in[1];
  const float* B  = (const float*)d_in[2];
  const float* Cm = (const float*)d_in[3];
  const float* Dp = (const float*)d_in[4];
  const float* ld = (const float*)d_in[5];
  float* out = (float*)d_out;
  float* ws = (float*)d_ws;

  // 4 K-slabs if workspace allows (10.2 MB), else 2 (6.2 MB)
  const size_t need4 =
      (size_t)(16384 + 4 * VSLAB + VSLAB + 16384 + 16384 + 2048) * 4;
  const int nslab = (ws_size >= need4) ? 4 : 2;

  float* invdT = ws;                       // 4096
  float* dA    = ws + 4096;                // 4096
  float* dA32  = ws + 8192;                // 4096
  float* dA512 = ws + 12288;               // 4096
  float* V     = ws + 16384;               // nslab * 524288
  float* U     = V + (size_t)nslab * VSLAB; // 524288
  float* S     = U + VSLAB;                // 16384
  float* Hinit = S + 16384;                // 16384
  float* S2g   = Hinit + 16384;            // 1024
  float* H2g   = S2g + 1024;               // 1024
  float* Ht    = V;                         // overlay: V dead after scan1

  main_kernel<<<nslab * 256 + 1, 256, 0, stream>>>(X, A, B, ld, invdT, dA, V,
                                                   2048 / nslab);
  scan1_kernel<<<NC1 + 1, 256, 0, stream>>>(V, invdT, dA, U, S, dA32, dA512, nslab);
  mid1_kernel<<<16, 64, 0, stream>>>(S, dA32, S2g);
  mid2_kernel<<<1, 64, 0, stream>>>(S2g, dA512, H2g);
  mid3_kernel<<<16, 64, 0, stream>>>(S, dA32, H2g, Hinit);
  scan2_kernel<<<NC1, 64, 0, stream>>>(U, dA, Hinit, Ht);
  out_kernel<<<dim3(128, 32), 256, 0, stream>>>(X, Cm, Dp, Ht, out);
}